// Round 7
// baseline (97.590 us; speedup 1.0000x reference)
//
#include <hip/hip_runtime.h>

#define BETA_F 0.001f
constexpr int Bn = 8192, Dd = 1024, Kk = 2048, Ee = 512;

// ---------------------------------------------------------------------------
// Collapsed pipeline (validated through R13, absmax 0.0 every round):
//   m_e  = mean_k rec_w[e,k]
//   t_k  = BETA*( (2/E)*sum_e m_e*rec_w[e,k] - (1/E)*sum_e rec_w[e,k]^2 )
//   yp   = softmax_k(t);  r*_d = sum_k yp_k * pw[k,d]
//   loss_b = mean_d (r*_d - images[b,d])^2
//
// Measured: R11 99.49 -> R13 97.22us. Fills ~86us (2x268MB, untouchable);
// our chain ~11.2us vs ~7.5us data floor (48MB @ 6.3TB/s) + 2 gaps.
// R14 single-variable change: loss_wave -> 2 rows/wave, u hoisted to regs and
// pre-scaled by 1/S once per wave, both rows' loads issued up-front (ILP-8).
// Same traffic, ~40% fewer VMEM issues on the 32MB stream, grid 1024 blocks.
// Prediction: -1..-2us if loss was issue-bound; +-0.3 if pure BW-bound (then
// roofline). Per-row arithmetic order preserved -> bitwise-identical output.
// ---------------------------------------------------------------------------

// Fused row-mean + column partial stats over a 4-row chunk of rec_w (E,K):
// grid 128 x 512 thr; thread owns one float4 column-group of all 4 rows.
// In-block row means (512 thr = 2048 floats = full row). Direct partial
// stores, no atomics. Block 0 zeroes u + S for the NEXT dispatch (stream-
// ordered, re-zeroed every replay) - no hipMemsetAsync anywhere.
__global__ __launch_bounds__(512) void stats_fused(
    const float* __restrict__ w,
    float* __restrict__ tm_part, float* __restrict__ tsq_part,
    float* __restrict__ u, float* __restrict__ Ssum)
{
    __shared__ float red[8][4];    // per-wave row sums
    __shared__ float sm_m[4];      // the 4 row means
    const int t = threadIdx.x;
    const int lane = t & 63, wv = t >> 6;
    const int eb = blockIdx.x;
    const int e0 = eb * 4;
    const float4* wp = (const float4*)w;             // (E, K/4 = 512)

    float4 vs[4];
    #pragma unroll
    for (int j = 0; j < 4; j++)
        vs[j] = wp[(size_t)(e0 + j) * (Kk / 4) + t];

    #pragma unroll
    for (int j = 0; j < 4; j++) {
        float s = (vs[j].x + vs[j].y) + (vs[j].z + vs[j].w);
        #pragma unroll
        for (int off = 32; off > 0; off >>= 1) s += __shfl_xor(s, off);
        if (lane == 0) red[wv][j] = s;
    }
    __syncthreads();
    if (t < 4) {
        float s = 0.f;
        #pragma unroll
        for (int g = 0; g < 8; g++) s += red[g][t];
        sm_m[t] = s * (1.f / (float)Kk);
    }
    __syncthreads();

    float4 sm = {0.f, 0.f, 0.f, 0.f}, sq = {0.f, 0.f, 0.f, 0.f};
    #pragma unroll
    for (int j = 0; j < 4; j++) {
        float mv = sm_m[j];
        sm.x += mv * vs[j].x; sm.y += mv * vs[j].y;
        sm.z += mv * vs[j].z; sm.w += mv * vs[j].w;
        sq.x += vs[j].x * vs[j].x; sq.y += vs[j].y * vs[j].y;
        sq.z += vs[j].z * vs[j].z; sq.w += vs[j].w * vs[j].w;
    }
    ((float4*)(tm_part  + (size_t)eb * Kk))[t] = sm;
    ((float4*)(tsq_part + (size_t)eb * Kk))[t] = sq;

    if (eb == 0) {
        if (t < 256) {
            float4 z = {0.f, 0.f, 0.f, 0.f};
            ((float4*)u)[t] = z;                     // 1024 floats
        }
        if (t == 0) *Ssum = 0.f;
    }
}

// Fused reduce_t + softmax-numerator + rstar accumulation. Grid 128 blocks,
// each owns 16 k-rows of project_w. Prologue: reduce the 128 eb-partials for
// this block's 16 k's (thread (kl,g) sums ebs 8g..8g+7; LDS tree finishes),
// t<16 computes t_k and exp(t_k) (|t|<1e-2 - no max-subtraction needed).
// One atomicAdd of the block's 16-exp partial into the global denominator S.
// Main body: u_d += sum_j exp(t_j) * pw[k0+j, d]  (unnormalized; /S deferred
// to loss). pw loads issued FIRST so HBM latency hides the prologue.
__global__ __launch_bounds__(256) void rstar_fused(
    const float* __restrict__ tm_part, const float* __restrict__ tsq_part,
    const float* __restrict__ pw, float* __restrict__ u,
    float* __restrict__ Ssum)
{
    __shared__ float sm_tm[256], sm_ts[256], sm_e[16];
    const int t = threadIdx.x;
    const int k0 = blockIdx.x * 16;

    // issue the 16 project_w row loads early (64 VGPRs of ILP)
    const float4* pwp = (const float4*)pw;           // (K, D/4 = 256)
    float4 vs[16];
    #pragma unroll
    for (int j = 0; j < 16; j++)
        vs[j] = pwp[(size_t)(k0 + j) * (Dd / 4) + t];

    // per-thread partial: k = k0 + (t&15), ebs [8g, 8g+8), g = t>>4
    const int kl = t & 15, g = t >> 4;
    const int k = k0 + kl;
    float ptm = 0.f, pts = 0.f;
    #pragma unroll
    for (int j = 0; j < 8; j++) {
        ptm += tm_part[(size_t)(8 * g + j) * Kk + k];
        pts += tsq_part[(size_t)(8 * g + j) * Kk + k];
    }
    sm_tm[t] = ptm; sm_ts[t] = pts;
    __syncthreads();
    if (t < 16) {
        float tmv = 0.f, tsv = 0.f;
        #pragma unroll
        for (int gg = 0; gg < 16; gg++) {
            tmv += sm_tm[gg * 16 + t];
            tsv += sm_ts[gg * 16 + t];
        }
        float tk = BETA_F * ((2.f / (float)Ee) * tmv - tsv * (1.f / (float)Ee));
        sm_e[t] = __expf(tk);
    }
    __syncthreads();
    if (t == 0) {
        float s = 0.f;
        #pragma unroll
        for (int j = 0; j < 16; j++) s += sm_e[j];
        atomicAdd(Ssum, s);
    }
    float4 acc = {0.f, 0.f, 0.f, 0.f};
    #pragma unroll
    for (int j = 0; j < 16; j++) {
        float wv = sm_e[j];
        acc.x += wv * vs[j].x; acc.y += wv * vs[j].y;
        acc.z += wv * vs[j].z; acc.w += wv * vs[j].w;
    }
    int d = t * 4;
    atomicAdd(&u[d + 0], acc.x); atomicAdd(&u[d + 1], acc.y);
    atomicAdd(&u[d + 2], acc.z); atomicAdd(&u[d + 3], acc.w);
}

// loss[b] = (1/D) * sum_d (u[d]/S - img[b,d])^2
// 2 rows per wave: u hoisted to 4 float4 regs, pre-scaled by 1/S once per
// wave (same r.x*inv values as before -> bitwise identical). Both rows'
// image loads issued up-front (8 dwordx4 in flight). Grid 1024 x 4 waves.
__global__ __launch_bounds__(256) void loss_wave(
    const float* __restrict__ img, const float* __restrict__ u,
    const float* __restrict__ Ssum, float* __restrict__ loss)
{
    const int lane = threadIdx.x & 63;
    const int wv   = threadIdx.x >> 6;
    const int row0 = (blockIdx.x * 4 + wv) * 2;      // 2 consecutive rows
    const float inv = 1.f / (*Ssum);                 // wave-uniform scalar load
    const float4* up = (const float4*)u;

    float4 ru[4];
    #pragma unroll
    for (int j = 0; j < 4; j++) {
        float4 r = up[lane + 64 * j];                // L1/L2-hot 4 KB, once
        ru[j].x = r.x * inv; ru[j].y = r.y * inv;
        ru[j].z = r.z * inv; ru[j].w = r.w * inv;
    }

    const float4* xp = (const float4*)(img + (size_t)row0 * Dd);
    float4 xa[4], xb[4];
    #pragma unroll
    for (int j = 0; j < 4; j++) xa[j] = xp[lane + 64 * j];
    #pragma unroll
    for (int j = 0; j < 4; j++) xb[j] = xp[256 + lane + 64 * j];

    float s0 = 0.f, s1 = 0.f;
    #pragma unroll
    for (int j = 0; j < 4; j++) {
        float dx = ru[j].x - xa[j].x, dy = ru[j].y - xa[j].y,
              dz = ru[j].z - xa[j].z, dw = ru[j].w - xa[j].w;
        s0 += dx * dx + dy * dy + dz * dz + dw * dw;
    }
    #pragma unroll
    for (int j = 0; j < 4; j++) {
        float dx = ru[j].x - xb[j].x, dy = ru[j].y - xb[j].y,
              dz = ru[j].z - xb[j].z, dw = ru[j].w - xb[j].w;
        s1 += dx * dx + dy * dy + dz * dz + dw * dw;
    }
    #pragma unroll
    for (int off = 32; off > 0; off >>= 1) {
        s0 += __shfl_xor(s0, off);
        s1 += __shfl_xor(s1, off);
    }
    if (lane == 0) {
        loss[row0]     = s0 * (1.f / (float)Dd);
        loss[row0 + 1] = s1 * (1.f / (float)Dd);
    }
}

extern "C" void kernel_launch(void* const* d_in, const int* in_sizes, int n_in,
                              void* d_out, int out_size, void* d_ws, size_t ws_size,
                              hipStream_t stream) {
    const float* images    = (const float*)d_in[0];   // (B, D)
    const float* project_w = (const float*)d_in[1];   // (K, D)
    const float* rec_w     = (const float*)d_in[2];   // (E, K)
    float* loss_out = (float*)d_out;                  // (B,)

    // workspace: tm_part(128K) | tsq_part(128K) | u(D) | S(+pad)
    float* tm_part  = (float*)d_ws;
    float* tsq_part = tm_part + 128 * Kk;
    float* u        = tsq_part + 128 * Kk;
    float* Ssum     = u + Dd;            // own 128B line (u ends at +1024)

    stats_fused<<<128, 512, 0, stream>>>(rec_w, tm_part, tsq_part, u, Ssum);
    rstar_fused<<<Kk / 16, 256, 0, stream>>>(tm_part, tsq_part, project_w, u, Ssum);
    loss_wave<<<Bn / 8, 256, 0, stream>>>(images, u, Ssum, loss_out);
}